// Round 12
// baseline (1925.035 us; speedup 1.0000x reference)
//
#include <hip/hip_runtime.h>
#include <hip/hip_bf16.h>
#include <cstdio>
#include <cstdint>

#define T_TOK   8192
#define H_DIM   1024
#define I_DIM   2048
#define E_NUM   8
#define BM      256
#define BN      256
#define BK2     32
#define PADMAX  18432         // T*K + E*BM
#define MAX_TILES 72          // T*K/BM + E

#define OUT_FRAC  8388608
#define OUT_AVG   8388616
#define OUT_LOG   8388624
#define OUT_PROB  8454160

typedef short short8v __attribute__((ext_vector_type(8)));
typedef float f32x4   __attribute__((ext_vector_type(4)));
typedef unsigned int u32x4 __attribute__((ext_vector_type(4)));

#define AS1 __attribute__((address_space(1)))
#define AS3 __attribute__((address_space(3)))
__device__ __forceinline__ void gload16(const void* g, void* l){
  __builtin_amdgcn_global_load_lds((const AS1 void*)g, (AS3 void*)l, 16, 0, 0);
}

#define WAITV3_BAR asm volatile("s_waitcnt vmcnt(3)\n\ts_barrier" ::: "memory")
#define WAITV2_BAR asm volatile("s_waitcnt vmcnt(2)\n\ts_barrier" ::: "memory")
#define WAITV0_BAR asm volatile("s_waitcnt vmcnt(0)\n\ts_barrier" ::: "memory")
#define SBAR  __builtin_amdgcn_s_barrier()
#define SCHED0 __builtin_amdgcn_sched_barrier(0)

__device__ __forceinline__ uint32_t f2bf(float f){
  union { float f; uint32_t u; } v; v.f = f;
  return (v.u + 0x7FFFu + ((v.u >> 16) & 1u)) >> 16;   // RNE
}
__device__ __forceinline__ uint32_t pack2(float a, float b){
  return f2bf(a) | (f2bf(b) << 16);
}
__device__ __forceinline__ float bflo(uint32_t u){ union{uint32_t u;float f;}v; v.u = u<<16; return v.f; }
__device__ __forceinline__ float bfhi(uint32_t u){ union{uint32_t u;float f;}v; v.u = u & 0xFFFF0000u; return v.f; }

// ---------------- fused fp32 -> bf16 bulk convert (x, gw, uw, dw) ----------------
#define NXB  (T_TOK*H_DIM/2048)          // 4096
#define NWB  (E_NUM*I_DIM*H_DIM/2048)    // 8192
__global__ __launch_bounds__(256) void convert4_kernel(
    const float* __restrict__ x,  const float* __restrict__ gw,
    const float* __restrict__ uw, const float* __restrict__ dw,
    ushort* __restrict__ xb, ushort* __restrict__ gwb,
    ushort* __restrict__ uwb, ushort* __restrict__ dwb){
  const int b = blockIdx.x;
  const float* src; ushort* dst; size_t base;
  if (b < NXB)            { src = x;  dst = xb;  base = (size_t)b * 2048; }
  else if (b < NXB+NWB)   { src = gw; dst = gwb; base = (size_t)(b-NXB) * 2048; }
  else if (b < NXB+2*NWB) { src = uw; dst = uwb; base = (size_t)(b-NXB-NWB) * 2048; }
  else                    { src = dw; dst = dwb; base = (size_t)(b-NXB-2*NWB) * 2048; }
  size_t i = base + (size_t)threadIdx.x * 8;
  f32x4 f0 = *(const f32x4*)(src + i);
  f32x4 f1 = *(const f32x4*)(src + i + 4);
  u32x4 o;
  o.x = pack2(f0.x, f0.y); o.y = pack2(f0.z, f0.w);
  o.z = pack2(f1.x, f1.y); o.w = pack2(f1.z, f1.w);
  *(u32x4*)(dst + i) = o;
}

// ---------------- router: logits/softmax/top2 ----------------
__global__ __launch_bounds__(256) void router_kernel(const float* __restrict__ x,
    const float* __restrict__ rw, float* __restrict__ out,
    int* __restrict__ counts, int* __restrict__ pe, float* __restrict__ pw){
  __shared__ float s_rw[E_NUM * H_DIM];
  __shared__ float s_avg[E_NUM];
  const int tid = threadIdx.x;
  for (int i = tid; i < E_NUM*H_DIM/4; i += 256)
    ((float4*)s_rw)[i] = ((const float4*)rw)[i];
  if (tid < E_NUM) s_avg[tid] = 0.f;
  __syncthreads();
  const int lane = tid & 63;
  const int t = blockIdx.x * 4 + (tid >> 6);
  float acc[E_NUM];
  #pragma unroll
  for (int e=0;e<E_NUM;e++) acc[e] = 0.f;
  const float* xr = x + (size_t)t * H_DIM;
  for (int c=0;c<H_DIM/64;c++){
    float xv = xr[c*64 + lane];
    #pragma unroll
    for (int e=0;e<E_NUM;e++) acc[e] += xv * s_rw[e*H_DIM + c*64 + lane];
  }
  #pragma unroll
  for (int e=0;e<E_NUM;e++){
    #pragma unroll
    for (int off=32; off; off>>=1) acc[e] += __shfl_xor(acc[e], off);
  }
  if (lane == 0){
    float m = acc[0];
    #pragma unroll
    for (int e=1;e<E_NUM;e++) m = fmaxf(m, acc[e]);
    float p[E_NUM]; float s = 0.f;
    #pragma unroll
    for (int e=0;e<E_NUM;e++){ p[e] = __expf(acc[e]-m); s += p[e]; }
    float inv = 1.f/s;
    #pragma unroll
    for (int e=0;e<E_NUM;e++) p[e] *= inv;
    float* lg = out + OUT_LOG  + (size_t)t*E_NUM;
    float* pr = out + OUT_PROB + (size_t)t*E_NUM;
    #pragma unroll
    for (int e=0;e<E_NUM;e++){ lg[e] = acc[e]; pr[e] = p[e]; }
    #pragma unroll
    for (int e=0;e<E_NUM;e++) atomicAdd(&s_avg[e], p[e]);
    int e1 = 0; float p1 = p[0];
    #pragma unroll
    for (int e=1;e<E_NUM;e++) if (p[e] > p1){ p1 = p[e]; e1 = e; }
    int e2 = -1; float p2 = -1.f;
    #pragma unroll
    for (int e=0;e<E_NUM;e++) if (e != e1 && p[e] > p2){ p2 = p[e]; e2 = e; }
    float rs = 1.f/(p1+p2);
    pe[2*t]   = e1; pw[2*t]   = p1*rs;
    pe[2*t+1] = e2; pw[2*t+1] = p2*rs;
    atomicAdd(&counts[e1], 1);
    atomicAdd(&counts[e2], 1);
  }
  __syncthreads();
  if (tid < E_NUM) atomicAdd(out + OUT_AVG + tid, s_avg[tid]);
}

// ---------------- offsets + tile table + zero-fill pads ----------------
__global__ void offsets_kernel(const int* __restrict__ counts, int* __restrict__ pad_off,
                               int* __restrict__ tile_e, int* __restrict__ tile_r,
                               int* __restrict__ hdr, int* __restrict__ s_tok,
                               float* __restrict__ s_wt){
  if (threadIdx.x == 0){
    int base = 0, tt = 0;
    for (int e=0;e<E_NUM;e++){
      pad_off[e] = base;
      int nt = (counts[e] + BM - 1) / BM;
      for (int i=0;i<nt;i++){ tile_e[tt] = e; tile_r[tt] = base + i*BM; tt++; }
      base += nt * BM;
    }
    hdr[0] = tt; hdr[1] = base;
  }
  for (int i = threadIdx.x; i < PADMAX; i += blockDim.x){
    s_tok[i] = 0; s_wt[i] = 0.f;
  }
}

// ---------------- scatter pairs into expert-sorted order ----------------
__global__ __launch_bounds__(256) void scatter_kernel(const int* __restrict__ pe,
    const float* __restrict__ pw, const int* __restrict__ pad_off,
    int* __restrict__ cursors, int* __restrict__ s_tok, float* __restrict__ s_wt,
    int* __restrict__ slot_idx){
  int t = blockIdx.x * 256 + threadIdx.x;
  #pragma unroll
  for (int k=0;k<2;k++){
    int e = pe[2*t + k];
    int pos = atomicAdd(&cursors[e], 1);
    int idx = pad_off[e] + pos;
    s_tok[idx] = t;
    s_wt[idx]  = pw[2*t + k];
    slot_idx[2*t + k] = idx;
  }
}

// ---------------- gate+up GEMM: 256x256 tile, 1024 thr, 3-buf depth-2, fine phases ----------------
__global__ __launch_bounds__(1024) void gateup_kernel(
    const ushort* __restrict__ xb, const ushort* __restrict__ gwb,
    const ushort* __restrict__ uwb, const int* __restrict__ s_tok,
    const int* __restrict__ tile_e, const int* __restrict__ tile_r,
    const int* __restrict__ hdr, ushort* __restrict__ h1)
{
  const int tile = blockIdx.y;
  if (tile >= hdr[0]) return;
  __shared__ short sA[3][BM*BK2];     // 16 KB each
  __shared__ short sG[3][BN*BK2];     // 16 KB each
  __shared__ short sU[3][BN*BK2];     // total 144 KB
  const int e = tile_e[tile];
  const int row0 = tile_r[tile];
  const int n0 = blockIdx.x * BN;
  const int tid = threadIdx.x, lane = tid & 63, wid = tid >> 6;   // 16 waves

  // staging: thread tid -> row tid>>2 (0..255), lds chunk tid&3; source chunk XOR'd
  const int srow = tid >> 2;
  const int scg  = ((tid & 3) ^ ((tid >> 3) & 3)) * 8;
  const ushort* gA = xb  + (size_t)s_tok[row0 + srow] * H_DIM + scg;
  const ushort* gG = gwb + ((size_t)e*I_DIM + n0 + srow) * H_DIM + scg;
  const ushort* gU = uwb + ((size_t)e*I_DIM + n0 + srow) * H_DIM + scg;
  const int sBase = wid * 512;   // wave-uniform LDS base (shorts): 64 lanes x 16B

  // compute: 16 waves = 4(m) x 4(n), per-wave 64x64
  const int wm = (wid >> 2) * 64, wn = (wid & 3) * 64;
  const int lr = lane & 15, q = lane >> 4;
  const int swc = (q ^ ((lr >> 1) & 3)) * 8;

  f32x4 accG[4][4] = {};
  f32x4 accU[4][4] = {};

  // prologue: stage tiles 0,1
  gload16(gA,        &sA[0][sBase]);
  gload16(gG,        &sG[0][sBase]);
  gload16(gU,        &sU[0][sBase]);
  gload16(gA  + BK2, &sA[1][sBase]);
  gload16(gG  + BK2, &sG[1][sBase]);
  gload16(gU  + BK2, &sU[1][sBase]);
  WAITV3_BAR;   // tile0 landed; tile1 (3 loads) in flight

  const int NK = H_DIM / BK2;   // 32
  int b0 = 0, b1 = 1, b2 = 2;
  for (int kt = 0; kt < NK; ++kt){
    short8v a_[4], bg_[4], bu_[4];
    // ---- phase 1: A+G frag reads, stage A,G of kt+2, 16 MFMA accG ----
    #pragma unroll
    for (int mi=0;mi<4;mi++)
      a_[mi] = *(const short8v*)&sA[b0][(wm + mi*16 + lr)*BK2 + swc];
    #pragma unroll
    for (int ni=0;ni<4;ni++)
      bg_[ni] = *(const short8v*)&sG[b0][(wn + ni*16 + lr)*BK2 + swc];
    if (kt + 2 < NK){
      const int kof = (kt+2)*BK2;
      gload16(gA + kof, &sA[b2][sBase]);
      gload16(gG + kof, &sG[b2][sBase]);
    }
    SCHED0; SBAR; SCHED0;
    __builtin_amdgcn_s_setprio(1);
    #pragma unroll
    for (int ni=0;ni<4;ni++)
      #pragma unroll
      for (int mi=0;mi<4;mi++)
        accG[mi][ni] = __builtin_amdgcn_mfma_f32_16x16x32_bf16(a_[mi], bg_[ni], accG[mi][ni], 0,0,0);
    __builtin_amdgcn_s_setprio(0);
    SCHED0; SBAR;
    // ---- phase 2: U frag reads, stage U of kt+2, 16 MFMA accU ----
    #pragma unroll
    for (int ni=0;ni<4;ni++)
      bu_[ni] = *(const short8v*)&sU[b0][(wn + ni*16 + lr)*BK2 + swc];
    if (kt + 2 < NK){
      gload16(gU + (kt+2)*BK2, &sU[b2][sBase]);
    }
    SCHED0; SBAR; SCHED0;
    __builtin_amdgcn_s_setprio(1);
    #pragma unroll
    for (int ni=0;ni<4;ni++)
      #pragma unroll
      for (int mi=0;mi<4;mi++)
        accU[mi][ni] = __builtin_amdgcn_mfma_f32_16x16x32_bf16(a_[mi], bu_[ni], accU[mi][ni], 0,0,0);
    __builtin_amdgcn_s_setprio(0);
    SCHED0;
    if (kt + 2 < NK)      WAITV3_BAR;   // kt+1 landed; kt+2 (3 loads) in flight
    else if (kt + 1 < NK) WAITV0_BAR;
    int tb = b0; b0 = b1; b1 = b2; b2 = tb;
  }

  // epilogue: h1 = silu(g) * u  (bf16)
  #pragma unroll
  for (int mi=0;mi<4;mi++){
    #pragma unroll
    for (int r=0;r<4;r++){
      const int row = row0 + wm + mi*16 + q*4 + r;
      ushort* hp = h1 + (size_t)row * I_DIM + n0 + wn + lr;
      #pragma unroll
      for (int ni=0;ni<4;ni++){
        float g = accG[mi][ni][r], u = accU[mi][ni][r];
        float sv = g / (1.f + __expf(-g));
        hp[ni*16] = (ushort)f2bf(sv * u);
      }
    }
  }
}

// ---------------- down GEMM: 256x256 tile, 1024 thr, 3-buf depth-2, XCD pinned ----------------
__global__ __launch_bounds__(1024) void down_kernel(
    const ushort* __restrict__ h1, const ushort* __restrict__ dwb,
    const int* __restrict__ tile_e, const int* __restrict__ tile_r,
    const int* __restrict__ hdr, ushort* __restrict__ ds_out)
{
  // 1D grid 288: bid = 8j+xs; xcd = xs; column = xs>>1 (0..3); tile = (xs&1)*36 + j
  const int bid = blockIdx.x;
  const int j = bid >> 3, xs = bid & 7;
  const int tile = (xs & 1) * (MAX_TILES/2) + j;
  if (tile >= hdr[0]) return;
  const int n0 = (xs >> 1) * BN;
  __shared__ short sA[3][BM*BK2];     // 16 KB each
  __shared__ short sB[3][BN*BK2];     // 16 KB each — total 96 KB
  const int e = tile_e[tile];
  const int row0 = tile_r[tile];
  const int tid = threadIdx.x, lane = tid & 63, wid = tid >> 6;

  const int srow = tid >> 2;
  const int scg  = ((tid & 3) ^ ((tid >> 3) & 3)) * 8;
  const ushort* gA = h1  + (size_t)(row0 + srow) * I_DIM + scg;
  const ushort* gB = dwb + ((size_t)e*H_DIM + n0 + srow) * I_DIM + scg;
  const int sBase = wid * 512;

  const int wm = (wid >> 2) * 64, wn = (wid & 3) * 64;
  const int lr = lane & 15, q = lane >> 4;
  const int swc = (q ^ ((lr >> 1) & 3)) * 8;

  f32x4 acc[4][4] = {};

  gload16(gA,        &sA[0][sBase]);
  gload16(gB,        &sB[0][sBase]);
  gload16(gA  + BK2, &sA[1][sBase]);
  gload16(gB  + BK2, &sB[1][sBase]);
  WAITV2_BAR;

  const int NK = I_DIM / BK2;   // 64
  int b0 = 0, b1 = 1, b2 = 2;
  for (int kt = 0; kt < NK; ++kt){
    short8v a_[4], b_[4];
    // ---- phase 1: A + B[0..1] frag reads, stage A of kt+2, 8 MFMA ----
    #pragma unroll
    for (int mi=0;mi<4;mi++)
      a_[mi] = *(const short8v*)&sA[b0][(wm + mi*16 + lr)*BK2 + swc];
    #pragma unroll
    for (int ni=0;ni<2;ni++)
      b_[ni] = *(const short8v*)&sB[b0][(wn + ni*16 + lr)*BK2 + swc];
    if (kt + 2 < NK){
      gload16(gA + (kt+2)*BK2, &sA[b2][sBase]);
    }
    SCHED0; SBAR; SCHED0;
    __builtin_amdgcn_s_setprio(1);
    #pragma unroll
    for (int ni=0;ni<2;ni++)
      #pragma unroll
      for (int mi=0;mi<4;mi++)
        acc[mi][ni] = __builtin_amdgcn_mfma_f32_16x16x32_bf16(a_[mi], b_[ni], acc[mi][ni], 0,0,0);
    __builtin_amdgcn_s_setprio(0);
    SCHED0; SBAR;
    // ---- phase 2: B[2..3] frag reads, stage B of kt+2, 8 MFMA ----
    #pragma unroll
    for (int ni=2;ni<4;ni++)
      b_[ni] = *(const short8v*)&sB[b0][(wn + ni*16 + lr)*BK2 + swc];
    if (kt + 2 < NK){
      gload16(gB + (kt+2)*BK2, &sB[b2][sBase]);
    }
    SCHED0; SBAR; SCHED0;
    __builtin_amdgcn_s_setprio(1);
    #pragma unroll
    for (int ni=2;ni<4;ni++)
      #pragma unroll
      for (int mi=0;mi<4;mi++)
        acc[mi][ni] = __builtin_amdgcn_mfma_f32_16x16x32_bf16(a_[mi], b_[ni], acc[mi][ni], 0,0,0);
    __builtin_amdgcn_s_setprio(0);
    SCHED0;
    if (kt + 2 < NK)      WAITV2_BAR;
    else if (kt + 1 < NK) WAITV0_BAR;
    int tb = b0; b0 = b1; b1 = b2; b2 = tb;
  }

  #pragma unroll
  for (int mi=0;mi<4;mi++){
    #pragma unroll
    for (int r=0;r<4;r++){
      const int prow = row0 + wm + mi*16 + q*4 + r;
      ushort* op = ds_out + (size_t)prow * H_DIM + n0 + wn + lr;
      #pragma unroll
      for (int ni=0;ni<4;ni++)
        op[ni*16] = (ushort)f2bf(acc[mi][ni][r]);
    }
  }
}

// ---------------- combine: out[t] = w1*ds[s1] + w2*ds[s2] ----------------
__global__ __launch_bounds__(256) void combine_kernel(const ushort* __restrict__ ds_out,
    const int* __restrict__ slot_idx, const float* __restrict__ s_wt,
    float* __restrict__ out){
  const int t   = blockIdx.x * 2 + (threadIdx.x >> 7);
  const int col = (threadIdx.x & 127) * 8;
  const int s1 = slot_idx[2*t], s2 = slot_idx[2*t+1];
  const float w1 = s_wt[s1], w2 = s_wt[s2];
  const u32x4 a = *(const u32x4*)(ds_out + (size_t)s1 * H_DIM + col);
  const u32x4 b = *(const u32x4*)(ds_out + (size_t)s2 * H_DIM + col);
  float* op = out + (size_t)t * H_DIM + col;
  f32x4 o0, o1;
  o0.x = w1*bflo(a.x) + w2*bflo(b.x);
  o0.y = w1*bfhi(a.x) + w2*bfhi(b.x);
  o0.z = w1*bflo(a.y) + w2*bflo(b.y);
  o0.w = w1*bfhi(a.y) + w2*bfhi(b.y);
  o1.x = w1*bflo(a.z) + w2*bflo(b.z);
  o1.y = w1*bfhi(a.z) + w2*bfhi(b.z);
  o1.z = w1*bflo(a.w) + w2*bflo(b.w);
  o1.w = w1*bfhi(a.w) + w2*bfhi(b.w);
  *(f32x4*)op       = o0;
  *(f32x4*)(op + 4) = o1;
}

// ---------------- finalize expert_frac / avg_prob ----------------
__global__ void finalize_kernel(const int* __restrict__ counts, float* __restrict__ out){
  int t = threadIdx.x;
  if (t < E_NUM){
    out[OUT_FRAC + t] = (float)counts[t] * (1.f/16384.f);
    out[OUT_AVG  + t] *= (1.f/8192.f);
  }
}

extern "C" void kernel_launch(void* const* d_in, const int* in_sizes, int n_in,
                              void* d_out, int out_size, void* d_ws, size_t ws_size,
                              hipStream_t stream){
  const float* x   = (const float*)d_in[0];
  const float* rw  = (const float*)d_in[1];
  const float* gw  = (const float*)d_in[2];
  const float* uw  = (const float*)d_in[3];
  const float* dwn = (const float*)d_in[4];
  float* out = (float*)d_out;

  char* w = (char*)d_ws;
  int*   counts   = (int*)(w + 0);
  int*   cursors  = (int*)(w + 32);
  int*   hdr      = (int*)(w + 64);
  int*   pad_off  = (int*)(w + 96);
  int*   tile_e   = (int*)(w + 256);
  int*   tile_r   = (int*)(w + 1024);
  int*   s_tok    = (int*)(w + 4096);                     // 18432*4
  float* s_wt     = (float*)(w + 77824);                  // 18432*4
  int*   pe       = (int*)(w + 151552);                   // 65536
  float* pw       = (float*)(w + 217088);                 // 65536
  int*   slot_idx = (int*)(w + 282624);                   // 65536
  ushort* xb      = (ushort*)(w + 348160);
  ushort* h1      = (ushort*)(w + 348160 + (size_t)T_TOK*H_DIM*2);
  ushort* gwb     = (ushort*)(w + 348160 + (size_t)T_TOK*H_DIM*2 + (size_t)PADMAX*I_DIM*2);
  ushort* uwb     = gwb + (size_t)E_NUM*I_DIM*H_DIM;
  ushort* dwb     = uwb + (size_t)E_NUM*I_DIM*H_DIM;
  ushort* ds_out  = gwb;   // overlay: gwb/uwb dead after gateup (67 MB >= 37.7 MB)

  size_t need = 348160 + (size_t)T_TOK*H_DIM*2 + (size_t)PADMAX*I_DIM*2
              + 3ull * E_NUM*I_DIM*H_DIM * 2;
  if (ws_size < need){
    fprintf(stderr, "kernel_launch: ws too small (%zu < %zu)\n", ws_size, need);
    return;
  }

  hipMemsetAsync(out + OUT_FRAC, 0, (OUT_AVG + E_NUM - OUT_FRAC) * 4, stream);
  hipMemsetAsync(d_ws, 0, 4096, stream);
  convert4_kernel<<<NXB + 3*NWB, 256, 0, stream>>>(x, gw, uw, dwn, xb, gwb, uwb, dwb);
  router_kernel<<<T_TOK/4, 256, 0, stream>>>(x, rw, out, counts, pe, pw);
  offsets_kernel<<<1, 256, 0, stream>>>(counts, pad_off, tile_e, tile_r, hdr, s_tok, s_wt);
  scatter_kernel<<<T_TOK/256, 256, 0, stream>>>(pe, pw, pad_off, cursors, s_tok, s_wt, slot_idx);
  gateup_kernel<<<dim3(I_DIM/BN, MAX_TILES), 1024, 0, stream>>>(xb, gwb, uwb, s_tok, tile_e, tile_r, hdr, h1);
  down_kernel<<<8 * (MAX_TILES/2), 1024, 0, stream>>>(h1, dwb, tile_e, tile_r, hdr, ds_out);
  combine_kernel<<<T_TOK/2, 256, 0, stream>>>(ds_out, slot_idx, s_wt, out);
  finalize_kernel<<<1, 64, 0, stream>>>(counts, out);
}

// Round 13
// 623.300 us; speedup vs baseline: 3.0885x; 3.0885x over previous
//
#include <hip/hip_runtime.h>
#include <hip/hip_bf16.h>
#include <cstdio>
#include <cstdint>

#define T_TOK   8192
#define H_DIM   1024
#define I_DIM   2048
#define E_NUM   8
#define BM      128
#define BK2     32
#define PADMAX  17408         // T*K + E*BM
#define MAX_TILES 136         // T*K/BM + E

#define OUT_FRAC  8388608
#define OUT_AVG   8388616
#define OUT_LOG   8388624
#define OUT_PROB  8454160

typedef short short8v __attribute__((ext_vector_type(8)));
typedef float f32x4   __attribute__((ext_vector_type(4)));
typedef unsigned int u32x4 __attribute__((ext_vector_type(4)));

#define AS1 __attribute__((address_space(1)))
#define AS3 __attribute__((address_space(3)))
__device__ __forceinline__ void gload16(const void* g, void* l){
  __builtin_amdgcn_global_load_lds((const AS1 void*)g, (AS3 void*)l, 16, 0, 0);
}

#define WAITV6_BAR asm volatile("s_waitcnt vmcnt(6)\n\ts_barrier" ::: "memory")
#define WAITV4_BAR asm volatile("s_waitcnt vmcnt(4)\n\ts_barrier" ::: "memory")
#define WAITV0_BAR asm volatile("s_waitcnt vmcnt(0)\n\ts_barrier" ::: "memory")
#define SBAR  __builtin_amdgcn_s_barrier()
#define SCHED0 __builtin_amdgcn_sched_barrier(0)

__device__ __forceinline__ uint32_t f2bf(float f){
  union { float f; uint32_t u; } v; v.f = f;
  return (v.u + 0x7FFFu + ((v.u >> 16) & 1u)) >> 16;   // RNE
}
__device__ __forceinline__ uint32_t pack2(float a, float b){
  return f2bf(a) | (f2bf(b) << 16);
}
__device__ __forceinline__ float bflo(uint32_t u){ union{uint32_t u;float f;}v; v.u = u<<16; return v.f; }
__device__ __forceinline__ float bfhi(uint32_t u){ union{uint32_t u;float f;}v; v.u = u & 0xFFFF0000u; return v.f; }

// ---------------- fused fp32 -> bf16 bulk convert (x, gw, uw, dw) ----------------
#define NXB  (T_TOK*H_DIM/2048)          // 4096
#define NWB  (E_NUM*I_DIM*H_DIM/2048)    // 8192
__global__ __launch_bounds__(256) void convert4_kernel(
    const float* __restrict__ x,  const float* __restrict__ gw,
    const float* __restrict__ uw, const float* __restrict__ dw,
    ushort* __restrict__ xb, ushort* __restrict__ gwb,
    ushort* __restrict__ uwb, ushort* __restrict__ dwb){
  const int b = blockIdx.x;
  const float* src; ushort* dst; size_t base;
  if (b < NXB)            { src = x;  dst = xb;  base = (size_t)b * 2048; }
  else if (b < NXB+NWB)   { src = gw; dst = gwb; base = (size_t)(b-NXB) * 2048; }
  else if (b < NXB+2*NWB) { src = uw; dst = uwb; base = (size_t)(b-NXB-NWB) * 2048; }
  else                    { src = dw; dst = dwb; base = (size_t)(b-NXB-2*NWB) * 2048; }
  size_t i = base + (size_t)threadIdx.x * 8;
  f32x4 f0 = *(const f32x4*)(src + i);
  f32x4 f1 = *(const f32x4*)(src + i + 4);
  u32x4 o;
  o.x = pack2(f0.x, f0.y); o.y = pack2(f0.z, f0.w);
  o.z = pack2(f1.x, f1.y); o.w = pack2(f1.z, f1.w);
  *(u32x4*)(dst + i) = o;
}

// ---------------- router: logits/softmax/top2 ----------------
__global__ __launch_bounds__(256) void router_kernel(const float* __restrict__ x,
    const float* __restrict__ rw, float* __restrict__ out,
    int* __restrict__ counts, int* __restrict__ pe, float* __restrict__ pw){
  __shared__ float s_rw[E_NUM * H_DIM];
  __shared__ float s_avg[E_NUM];
  const int tid = threadIdx.x;
  for (int i = tid; i < E_NUM*H_DIM/4; i += 256)
    ((float4*)s_rw)[i] = ((const float4*)rw)[i];
  if (tid < E_NUM) s_avg[tid] = 0.f;
  __syncthreads();
  const int lane = tid & 63;
  const int t = blockIdx.x * 4 + (tid >> 6);
  float acc[E_NUM];
  #pragma unroll
  for (int e=0;e<E_NUM;e++) acc[e] = 0.f;
  const float* xr = x + (size_t)t * H_DIM;
  for (int c=0;c<H_DIM/64;c++){
    float xv = xr[c*64 + lane];
    #pragma unroll
    for (int e=0;e<E_NUM;e++) acc[e] += xv * s_rw[e*H_DIM + c*64 + lane];
  }
  #pragma unroll
  for (int e=0;e<E_NUM;e++){
    #pragma unroll
    for (int off=32; off; off>>=1) acc[e] += __shfl_xor(acc[e], off);
  }
  if (lane == 0){
    float m = acc[0];
    #pragma unroll
    for (int e=1;e<E_NUM;e++) m = fmaxf(m, acc[e]);
    float p[E_NUM]; float s = 0.f;
    #pragma unroll
    for (int e=0;e<E_NUM;e++){ p[e] = __expf(acc[e]-m); s += p[e]; }
    float inv = 1.f/s;
    #pragma unroll
    for (int e=0;e<E_NUM;e++) p[e] *= inv;
    float* lg = out + OUT_LOG  + (size_t)t*E_NUM;
    float* pr = out + OUT_PROB + (size_t)t*E_NUM;
    #pragma unroll
    for (int e=0;e<E_NUM;e++){ lg[e] = acc[e]; pr[e] = p[e]; }
    #pragma unroll
    for (int e=0;e<E_NUM;e++) atomicAdd(&s_avg[e], p[e]);
    int e1 = 0; float p1 = p[0];
    #pragma unroll
    for (int e=1;e<E_NUM;e++) if (p[e] > p1){ p1 = p[e]; e1 = e; }
    int e2 = -1; float p2 = -1.f;
    #pragma unroll
    for (int e=0;e<E_NUM;e++) if (e != e1 && p[e] > p2){ p2 = p[e]; e2 = e; }
    float rs = 1.f/(p1+p2);
    pe[2*t]   = e1; pw[2*t]   = p1*rs;
    pe[2*t+1] = e2; pw[2*t+1] = p2*rs;
    atomicAdd(&counts[e1], 1);
    atomicAdd(&counts[e2], 1);
  }
  __syncthreads();
  if (tid < E_NUM) atomicAdd(out + OUT_AVG + tid, s_avg[tid]);
}

// ---------------- offsets + tile table + zero-fill pads ----------------
__global__ void offsets_kernel(const int* __restrict__ counts, int* __restrict__ pad_off,
                               int* __restrict__ tile_e, int* __restrict__ tile_r,
                               int* __restrict__ hdr, int* __restrict__ s_tok,
                               float* __restrict__ s_wt){
  if (threadIdx.x == 0){
    int base = 0, tt = 0;
    for (int e=0;e<E_NUM;e++){
      pad_off[e] = base;
      int nt = (counts[e] + BM - 1) / BM;
      for (int i=0;i<nt;i++){ tile_e[tt] = e; tile_r[tt] = base + i*BM; tt++; }
      base += nt * BM;
    }
    hdr[0] = tt; hdr[1] = base;
  }
  for (int i = threadIdx.x; i < PADMAX; i += blockDim.x){
    s_tok[i] = 0; s_wt[i] = 0.f;
  }
}

// ---------------- scatter pairs into expert-sorted order ----------------
__global__ __launch_bounds__(256) void scatter_kernel(const int* __restrict__ pe,
    const float* __restrict__ pw, const int* __restrict__ pad_off,
    int* __restrict__ cursors, int* __restrict__ s_tok, float* __restrict__ s_wt,
    int* __restrict__ slot_idx){
  int t = blockIdx.x * 256 + threadIdx.x;
  #pragma unroll
  for (int k=0;k<2;k++){
    int e = pe[2*t + k];
    int pos = atomicAdd(&cursors[e], 1);
    int idx = pad_off[e] + pos;
    s_tok[idx] = t;
    s_wt[idx]  = pw[2*t + k];
    slot_idx[2*t + k] = idx;
  }
}

// ---------------- gate+up GEMM: 128x128 tile, 256 thr (4 waves), 3-buf, 2 blocks/CU ----------------
__global__ __launch_bounds__(256, 2) void gateup_kernel(
    const ushort* __restrict__ xb, const ushort* __restrict__ gwb,
    const ushort* __restrict__ uwb, const int* __restrict__ s_tok,
    const int* __restrict__ tile_e, const int* __restrict__ tile_r,
    const int* __restrict__ hdr, ushort* __restrict__ h1)
{
  const int tile = blockIdx.y;
  if (tile >= hdr[0]) return;
  __shared__ short sA[3][BM*BK2];     // 8 KB per buf
  __shared__ short sG[3][BM*BK2];     // 8 KB per buf
  __shared__ short sU[3][BM*BK2];     // 8 KB per buf — total 72 KB -> 2 blocks/CU
  const int e = tile_e[tile];
  const int row0 = tile_r[tile];
  const int n0 = blockIdx.x * 128;
  const int tid = threadIdx.x, lane = tid & 63, wid = tid >> 6;   // 4 waves

  // staging: slot = tid (+256): row = slot>>2, lds chunk = slot&3; source chunk XOR'd.
  // dest byte = slot*16 (linear in tid -> wave-uniform base + lane*16)
  const int srow = tid >> 2;                                 // 0..63
  const int scg  = ((tid & 3) ^ ((tid >> 3) & 3)) * 8;       // swizzled source chunk
  const int d0 = tid * 8, d1 = tid * 8 + 2048;               // shorts
  const ushort* gA0 = xb  + (size_t)s_tok[row0 + srow]      * H_DIM + scg;
  const ushort* gA1 = xb  + (size_t)s_tok[row0 + srow + 64] * H_DIM + scg;
  const ushort* gG0 = gwb + ((size_t)e*I_DIM + n0 + srow)      * H_DIM + scg;
  const ushort* gG1 = gwb + ((size_t)e*I_DIM + n0 + srow + 64) * H_DIM + scg;
  const ushort* gU0 = uwb + ((size_t)e*I_DIM + n0 + srow)      * H_DIM + scg;
  const ushort* gU1 = uwb + ((size_t)e*I_DIM + n0 + srow + 64) * H_DIM + scg;

  // compute: 4 waves = 2(m) x 2(n), per-wave 64x64
  const int wm = (wid >> 1) * 64, wn = (wid & 1) * 64;
  const int lr = lane & 15, q = lane >> 4;
  const int swc = (q ^ ((lr >> 1) & 3)) * 8;

  f32x4 accG[4][4] = {};
  f32x4 accU[4][4] = {};

  // prologue: stage tiles 0,1 (6 loads each)
  gload16(gA0,       &sA[0][d0]); gload16(gA1,       &sA[0][d1]);
  gload16(gG0,       &sG[0][d0]); gload16(gG1,       &sG[0][d1]);
  gload16(gU0,       &sU[0][d0]); gload16(gU1,       &sU[0][d1]);
  gload16(gA0 + BK2, &sA[1][d0]); gload16(gA1 + BK2, &sA[1][d1]);
  gload16(gG0 + BK2, &sG[1][d0]); gload16(gG1 + BK2, &sG[1][d1]);
  gload16(gU0 + BK2, &sU[1][d0]); gload16(gU1 + BK2, &sU[1][d1]);
  WAITV6_BAR;   // tile0 landed; tile1 (6) in flight

  const int NK = H_DIM / BK2;   // 32
  int b0 = 0, b1 = 1, b2 = 2;
  for (int kt = 0; kt < NK; ++kt){
    short8v a_[4], bg_[4], bu_[4];
    // ---- phase 1: A+G frag reads, stage A,G of kt+2, 16 MFMA accG ----
    #pragma unroll
    for (int mi=0;mi<4;mi++)
      a_[mi] = *(const short8v*)&sA[b0][(wm + mi*16 + lr)*BK2 + swc];
    #pragma unroll
    for (int ni=0;ni<4;ni++)
      bg_[ni] = *(const short8v*)&sG[b0][(wn + ni*16 + lr)*BK2 + swc];
    if (kt + 2 < NK){
      const int kof = (kt+2)*BK2;
      gload16(gA0 + kof, &sA[b2][d0]); gload16(gA1 + kof, &sA[b2][d1]);
      gload16(gG0 + kof, &sG[b2][d0]); gload16(gG1 + kof, &sG[b2][d1]);
    }
    SCHED0; SBAR; SCHED0;
    __builtin_amdgcn_s_setprio(1);
    #pragma unroll
    for (int ni=0;ni<4;ni++)
      #pragma unroll
      for (int mi=0;mi<4;mi++)
        accG[mi][ni] = __builtin_amdgcn_mfma_f32_16x16x32_bf16(a_[mi], bg_[ni], accG[mi][ni], 0,0,0);
    __builtin_amdgcn_s_setprio(0);
    SCHED0; SBAR;
    // ---- phase 2: U frag reads, stage U of kt+2, 16 MFMA accU ----
    #pragma unroll
    for (int ni=0;ni<4;ni++)
      bu_[ni] = *(const short8v*)&sU[b0][(wn + ni*16 + lr)*BK2 + swc];
    if (kt + 2 < NK){
      const int kof = (kt+2)*BK2;
      gload16(gU0 + kof, &sU[b2][d0]); gload16(gU1 + kof, &sU[b2][d1]);
    }
    SCHED0; SBAR; SCHED0;
    __builtin_amdgcn_s_setprio(1);
    #pragma unroll
    for (int ni=0;ni<4;ni++)
      #pragma unroll
      for (int mi=0;mi<4;mi++)
        accU[mi][ni] = __builtin_amdgcn_mfma_f32_16x16x32_bf16(a_[mi], bu_[ni], accU[mi][ni], 0,0,0);
    __builtin_amdgcn_s_setprio(0);
    SCHED0;
    if (kt + 2 < NK)      WAITV6_BAR;   // kt+1 landed; kt+2 (6) in flight
    else if (kt + 1 < NK) WAITV0_BAR;
    int tb = b0; b0 = b1; b1 = b2; b2 = tb;
  }

  // epilogue: h1 = silu(g) * u  (bf16)
  #pragma unroll
  for (int mi=0;mi<4;mi++){
    #pragma unroll
    for (int r=0;r<4;r++){
      const int row = row0 + wm + mi*16 + q*4 + r;
      ushort* hp = h1 + (size_t)row * I_DIM + n0 + wn + lr;
      #pragma unroll
      for (int ni=0;ni<4;ni++){
        float g = accG[mi][ni][r], u = accU[mi][ni][r];
        float sv = g / (1.f + __expf(-g));
        hp[ni*16] = (ushort)f2bf(sv * u);
      }
    }
  }
}

// ---------------- down GEMM: 128x128 tile, 256 thr, 3-buf, 3 blocks/CU ----------------
__global__ __launch_bounds__(256, 3) void down_kernel(
    const ushort* __restrict__ h1, const ushort* __restrict__ dwb,
    const int* __restrict__ tile_e, const int* __restrict__ tile_r,
    const int* __restrict__ hdr, ushort* __restrict__ ds_out)
{
  const int tile = blockIdx.y;
  if (tile >= hdr[0]) return;
  __shared__ short sA[3][BM*BK2];     // 8 KB per buf
  __shared__ short sB[3][BM*BK2];     // 8 KB per buf — total 48 KB -> 3 blocks/CU
  const int e = tile_e[tile];
  const int row0 = tile_r[tile];
  const int n0 = blockIdx.x * 128;
  const int tid = threadIdx.x, lane = tid & 63, wid = tid >> 6;

  const int srow = tid >> 2;
  const int scg  = ((tid & 3) ^ ((tid >> 3) & 3)) * 8;
  const int d0 = tid * 8, d1 = tid * 8 + 2048;
  const ushort* gA0 = h1  + (size_t)(row0 + srow)      * I_DIM + scg;
  const ushort* gA1 = h1  + (size_t)(row0 + srow + 64) * I_DIM + scg;
  const ushort* gB0 = dwb + ((size_t)e*H_DIM + n0 + srow)      * I_DIM + scg;
  const ushort* gB1 = dwb + ((size_t)e*H_DIM + n0 + srow + 64) * I_DIM + scg;

  const int wm = (wid >> 1) * 64, wn = (wid & 1) * 64;
  const int lr = lane & 15, q = lane >> 4;
  const int swc = (q ^ ((lr >> 1) & 3)) * 8;

  f32x4 acc[4][4] = {};

  gload16(gA0,       &sA[0][d0]); gload16(gA1,       &sA[0][d1]);
  gload16(gB0,       &sB[0][d0]); gload16(gB1,       &sB[0][d1]);
  gload16(gA0 + BK2, &sA[1][d0]); gload16(gA1 + BK2, &sA[1][d1]);
  gload16(gB0 + BK2, &sB[1][d0]); gload16(gB1 + BK2, &sB[1][d1]);
  WAITV4_BAR;

  const int NK = I_DIM / BK2;   // 64
  int b0 = 0, b1 = 1, b2 = 2;
  for (int kt = 0; kt < NK; ++kt){
    short8v a_[4], b_[4];
    // ---- phase 1: A + B[0..1] frag reads, stage A of kt+2, 8 MFMA ----
    #pragma unroll
    for (int mi=0;mi<4;mi++)
      a_[mi] = *(const short8v*)&sA[b0][(wm + mi*16 + lr)*BK2 + swc];
    #pragma unroll
    for (int ni=0;ni<2;ni++)
      b_[ni] = *(const short8v*)&sB[b0][(wn + ni*16 + lr)*BK2 + swc];
    if (kt + 2 < NK){
      const int kof = (kt+2)*BK2;
      gload16(gA0 + kof, &sA[b2][d0]); gload16(gA1 + kof, &sA[b2][d1]);
    }
    SCHED0; SBAR; SCHED0;
    __builtin_amdgcn_s_setprio(1);
    #pragma unroll
    for (int ni=0;ni<2;ni++)
      #pragma unroll
      for (int mi=0;mi<4;mi++)
        acc[mi][ni] = __builtin_amdgcn_mfma_f32_16x16x32_bf16(a_[mi], b_[ni], acc[mi][ni], 0,0,0);
    __builtin_amdgcn_s_setprio(0);
    SCHED0; SBAR;
    // ---- phase 2: B[2..3] frag reads, stage B of kt+2, 8 MFMA ----
    #pragma unroll
    for (int ni=2;ni<4;ni++)
      b_[ni] = *(const short8v*)&sB[b0][(wn + ni*16 + lr)*BK2 + swc];
    if (kt + 2 < NK){
      const int kof = (kt+2)*BK2;
      gload16(gB0 + kof, &sB[b2][d0]); gload16(gB1 + kof, &sB[b2][d1]);
    }
    SCHED0; SBAR; SCHED0;
    __builtin_amdgcn_s_setprio(1);
    #pragma unroll
    for (int ni=2;ni<4;ni++)
      #pragma unroll
      for (int mi=0;mi<4;mi++)
        acc[mi][ni] = __builtin_amdgcn_mfma_f32_16x16x32_bf16(a_[mi], b_[ni], acc[mi][ni], 0,0,0);
    __builtin_amdgcn_s_setprio(0);
    SCHED0;
    if (kt + 2 < NK)      WAITV4_BAR;
    else if (kt + 1 < NK) WAITV0_BAR;
    int tb = b0; b0 = b1; b1 = b2; b2 = tb;
  }

  #pragma unroll
  for (int mi=0;mi<4;mi++){
    #pragma unroll
    for (int r=0;r<4;r++){
      const int prow = row0 + wm + mi*16 + q*4 + r;
      ushort* op = ds_out + (size_t)prow * H_DIM + n0 + wn + lr;
      #pragma unroll
      for (int ni=0;ni<4;ni++)
        op[ni*16] = (ushort)f2bf(acc[mi][ni][r]);
    }
  }
}

// ---------------- combine: out[t] = w1*ds[s1] + w2*ds[s2] ----------------
__global__ __launch_bounds__(256) void combine_kernel(const ushort* __restrict__ ds_out,
    const int* __restrict__ slot_idx, const float* __restrict__ s_wt,
    float* __restrict__ out){
  const int t   = blockIdx.x * 2 + (threadIdx.x >> 7);
  const int col = (threadIdx.x & 127) * 8;
  const int s1 = slot_idx[2*t], s2 = slot_idx[2*t+1];
  const float w1 = s_wt[s1], w2 = s_wt[s2];
  const u32x4 a = *(const u32x4*)(ds_out + (size_t)s1 * H_DIM + col);
  const u32x4 b = *(const u32x4*)(ds_out + (size_t)s2 * H_DIM + col);
  float* op = out + (size_t)t * H_DIM + col;
  f32x4 o0, o1;
  o0.x = w1*bflo(a.x) + w2*bflo(b.x);
  o0.y = w1*bfhi(a.x) + w2*bfhi(b.x);
  o0.z = w1*bflo(a.y) + w2*bflo(b.y);
  o0.w = w1*bfhi(a.y) + w2*bfhi(b.y);
  o1.x = w1*bflo(a.z) + w2*bflo(b.z);
  o1.y = w1*bfhi(a.z) + w2*bfhi(b.z);
  o1.z = w1*bflo(a.w) + w2*bflo(b.w);
  o1.w = w1*bfhi(a.w) + w2*bfhi(b.w);
  *(f32x4*)op       = o0;
  *(f32x4*)(op + 4) = o1;
}

// ---------------- finalize expert_frac / avg_prob ----------------
__global__ void finalize_kernel(const int* __restrict__ counts, float* __restrict__ out){
  int t = threadIdx.x;
  if (t < E_NUM){
    out[OUT_FRAC + t] = (float)counts[t] * (1.f/16384.f);
    out[OUT_AVG  + t] *= (1.f/8192.f);
  }
}

extern "C" void kernel_launch(void* const* d_in, const int* in_sizes, int n_in,
                              void* d_out, int out_size, void* d_ws, size_t ws_size,
                              hipStream_t stream){
  const float* x   = (const float*)d_in[0];
  const float* rw  = (const float*)d_in[1];
  const float* gw  = (const float*)d_in[2];
  const float* uw  = (const float*)d_in[3];
  const float* dwn = (const float*)d_in[4];
  float* out = (float*)d_out;

  char* w = (char*)d_ws;
  int*   counts   = (int*)(w + 0);
  int*   cursors  = (int*)(w + 32);
  int*   hdr      = (int*)(w + 64);
  int*   pad_off  = (int*)(w + 96);
  int*   tile_e   = (int*)(w + 256);
  int*   tile_r   = (int*)(w + 1024);
  int*   s_tok    = (int*)(w + 4096);
  float* s_wt     = (float*)(w + 4096 + PADMAX*4);
  int*   pe       = (int*)(w + 4096 + PADMAX*8);
  float* pw       = (float*)(w + 4096 + PADMAX*8 + T_TOK*2*4);
  int*   slot_idx = (int*)(w + 4096 + PADMAX*8 + T_TOK*2*8);
  ushort* xb      = (ushort*)(w + 339968);
  ushort* h1      = (ushort*)(w + 339968 + (size_t)T_TOK*H_DIM*2);
  ushort* gwb     = (ushort*)(w + 339968 + (size_t)T_TOK*H_DIM*2 + (size_t)PADMAX*I_DIM*2);
  ushort* uwb     = gwb + (size_t)E_NUM*I_DIM*H_DIM;
  ushort* dwb     = uwb + (size_t)E_NUM*I_DIM*H_DIM;
  ushort* ds_out  = gwb;   // overlay: gwb/uwb are dead once gateup completes

  size_t need = 339968 + (size_t)T_TOK*H_DIM*2 + (size_t)PADMAX*I_DIM*2
              + 3ull * E_NUM*I_DIM*H_DIM * 2;
  if (ws_size < need){
    fprintf(stderr, "kernel_launch: ws too small (%zu < %zu)\n", ws_size, need);
    return;
  }

  hipMemsetAsync(out + OUT_FRAC, 0, (OUT_AVG + E_NUM - OUT_FRAC) * 4, stream);
  hipMemsetAsync(d_ws, 0, 4096, stream);
  convert4_kernel<<<NXB + 3*NWB, 256, 0, stream>>>(x, gw, uw, dwn, xb, gwb, uwb, dwb);
  router_kernel<<<T_TOK/4, 256, 0, stream>>>(x, rw, out, counts, pe, pw);
  offsets_kernel<<<1, 256, 0, stream>>>(counts, pad_off, tile_e, tile_r, hdr, s_tok, s_wt);
  scatter_kernel<<<T_TOK/256, 256, 0, stream>>>(pe, pw, pad_off, cursors, s_tok, s_wt, slot_idx);
  gateup_kernel<<<dim3(I_DIM/128, MAX_TILES), 256, 0, stream>>>(xb, gwb, uwb, s_tok, tile_e, tile_r, hdr, h1);
  down_kernel<<<dim3(H_DIM/128, MAX_TILES), 256, 0, stream>>>(h1, dwb, tile_e, tile_r, hdr, ds_out);
  combine_kernel<<<T_TOK/2, 256, 0, stream>>>(ds_out, slot_idx, s_wt, out);
  finalize_kernel<<<1, 64, 0, stream>>>(counts, out);
}

// Round 14
// 369.857 us; speedup vs baseline: 5.2048x; 1.6852x over previous
//
#include <hip/hip_runtime.h>
#include <hip/hip_bf16.h>
#include <cstdio>
#include <cstdint>

#define T_TOK   8192
#define H_DIM   1024
#define I_DIM   2048
#define E_NUM   8
#define BM      128
#define BK2     32
#define PADMAX  17408         // T*K + E*BM
#define MAX_TILES 136         // T*K/BM + E
#define HB      32            // histogram/scatter blocks
#define PAIRS_PER_HB (T_TOK*2/HB)   // 512

#define OUT_FRAC  8388608
#define OUT_AVG   8388616
#define OUT_LOG   8388624
#define OUT_PROB  8454160

typedef short short8v __attribute__((ext_vector_type(8)));
typedef float f32x4   __attribute__((ext_vector_type(4)));
typedef unsigned int u32x4 __attribute__((ext_vector_type(4)));

#define AS1 __attribute__((address_space(1)))
#define AS3 __attribute__((address_space(3)))
__device__ __forceinline__ void gload16(const void* g, void* l){
  __builtin_amdgcn_global_load_lds((const AS1 void*)g, (AS3 void*)l, 16, 0, 0);
}

#define WAITV6_BAR asm volatile("s_waitcnt vmcnt(6)\n\ts_barrier" ::: "memory")
#define WAITV4_BAR asm volatile("s_waitcnt vmcnt(4)\n\ts_barrier" ::: "memory")
#define WAITV0_BAR asm volatile("s_waitcnt vmcnt(0)\n\ts_barrier" ::: "memory")
#define SBAR  __builtin_amdgcn_s_barrier()
#define SCHED0 __builtin_amdgcn_sched_barrier(0)

__device__ __forceinline__ uint32_t f2bf(float f){
  union { float f; uint32_t u; } v; v.f = f;
  return (v.u + 0x7FFFu + ((v.u >> 16) & 1u)) >> 16;   // RNE
}
__device__ __forceinline__ uint32_t pack2(float a, float b){
  return f2bf(a) | (f2bf(b) << 16);
}
__device__ __forceinline__ float bflo(uint32_t u){ union{uint32_t u;float f;}v; v.u = u<<16; return v.f; }
__device__ __forceinline__ float bfhi(uint32_t u){ union{uint32_t u;float f;}v; v.u = u & 0xFFFF0000u; return v.f; }

// ---------------- fused fp32 -> bf16 bulk convert (x, gw, uw, dw) ----------------
#define NXB  (T_TOK*H_DIM/2048)          // 4096
#define NWB  (E_NUM*I_DIM*H_DIM/2048)    // 8192
__global__ __launch_bounds__(256) void convert4_kernel(
    const float* __restrict__ x,  const float* __restrict__ gw,
    const float* __restrict__ uw, const float* __restrict__ dw,
    ushort* __restrict__ xb, ushort* __restrict__ gwb,
    ushort* __restrict__ uwb, ushort* __restrict__ dwb){
  const int b = blockIdx.x;
  const float* src; ushort* dst; size_t base;
  if (b < NXB)            { src = x;  dst = xb;  base = (size_t)b * 2048; }
  else if (b < NXB+NWB)   { src = gw; dst = gwb; base = (size_t)(b-NXB) * 2048; }
  else if (b < NXB+2*NWB) { src = uw; dst = uwb; base = (size_t)(b-NXB-NWB) * 2048; }
  else                    { src = dw; dst = dwb; base = (size_t)(b-NXB-2*NWB) * 2048; }
  size_t i = base + (size_t)threadIdx.x * 8;
  f32x4 f0 = *(const f32x4*)(src + i);
  f32x4 f1 = *(const f32x4*)(src + i + 4);
  u32x4 o;
  o.x = pack2(f0.x, f0.y); o.y = pack2(f0.z, f0.w);
  o.z = pack2(f1.x, f1.y); o.w = pack2(f1.z, f1.w);
  *(u32x4*)(dst + i) = o;
}

// ---------------- router: logits/softmax/top2; per-block avg partials; NO global atomics ----------------
__global__ __launch_bounds__(256) void router_kernel(const float* __restrict__ x,
    const float* __restrict__ rw, float* __restrict__ out,
    int* __restrict__ pe, float* __restrict__ pw, float* __restrict__ avg_part){
  __shared__ float s_rw[E_NUM * H_DIM];
  __shared__ float s_avg[E_NUM];
  const int tid = threadIdx.x;
  for (int i = tid; i < E_NUM*H_DIM/4; i += 256)
    ((float4*)s_rw)[i] = ((const float4*)rw)[i];
  if (tid < E_NUM) s_avg[tid] = 0.f;
  __syncthreads();
  const int lane = tid & 63;
  const int t = blockIdx.x * 4 + (tid >> 6);
  float acc[E_NUM];
  #pragma unroll
  for (int e=0;e<E_NUM;e++) acc[e] = 0.f;
  const float* xr = x + (size_t)t * H_DIM;
  for (int c=0;c<H_DIM/64;c++){
    float xv = xr[c*64 + lane];
    #pragma unroll
    for (int e=0;e<E_NUM;e++) acc[e] += xv * s_rw[e*H_DIM + c*64 + lane];
  }
  #pragma unroll
  for (int e=0;e<E_NUM;e++){
    #pragma unroll
    for (int off=32; off; off>>=1) acc[e] += __shfl_xor(acc[e], off);
  }
  if (lane == 0){
    float m = acc[0];
    #pragma unroll
    for (int e=1;e<E_NUM;e++) m = fmaxf(m, acc[e]);
    float p[E_NUM]; float s = 0.f;
    #pragma unroll
    for (int e=0;e<E_NUM;e++){ p[e] = __expf(acc[e]-m); s += p[e]; }
    float inv = 1.f/s;
    #pragma unroll
    for (int e=0;e<E_NUM;e++) p[e] *= inv;
    float* lg = out + OUT_LOG  + (size_t)t*E_NUM;
    float* pr = out + OUT_PROB + (size_t)t*E_NUM;
    #pragma unroll
    for (int e=0;e<E_NUM;e++){ lg[e] = acc[e]; pr[e] = p[e]; }
    #pragma unroll
    for (int e=0;e<E_NUM;e++) atomicAdd(&s_avg[e], p[e]);   // LDS atomic (cheap)
    int e1 = 0; float p1 = p[0];
    #pragma unroll
    for (int e=1;e<E_NUM;e++) if (p[e] > p1){ p1 = p[e]; e1 = e; }
    int e2 = -1; float p2 = -1.f;
    #pragma unroll
    for (int e=0;e<E_NUM;e++) if (e != e1 && p[e] > p2){ p2 = p[e]; e2 = e; }
    float rs = 1.f/(p1+p2);
    pe[2*t]   = e1; pw[2*t]   = p1*rs;
    pe[2*t+1] = e2; pw[2*t+1] = p2*rs;
  }
  __syncthreads();
  if (tid < E_NUM) avg_part[blockIdx.x*E_NUM + tid] = s_avg[tid];
}

// ---------------- per-block expert histogram (LDS atomics only) ----------------
__global__ __launch_bounds__(256) void hist_kernel(const int* __restrict__ pe,
                                                   int* __restrict__ block_hist){
  __shared__ int h[E_NUM];
  if (threadIdx.x < E_NUM) h[threadIdx.x] = 0;
  __syncthreads();
  const int base = blockIdx.x * PAIRS_PER_HB;
  for (int i = threadIdx.x; i < PAIRS_PER_HB; i += 256)
    atomicAdd(&h[pe[base + i]], 1);
  __syncthreads();
  if (threadIdx.x < E_NUM) block_hist[blockIdx.x*E_NUM + threadIdx.x] = h[threadIdx.x];
}

// ---------------- offsets: counts/frac/avg + tile table + per-block bases + zero pads ----------------
__global__ __launch_bounds__(256) void offsets_kernel(const int* __restrict__ block_hist,
    const float* __restrict__ avg_part, int* __restrict__ block_base,
    int* __restrict__ tile_e, int* __restrict__ tile_r, int* __restrict__ hdr,
    int* __restrict__ s_tok, float* __restrict__ s_wt, float* __restrict__ out){
  __shared__ int counts[E_NUM];
  __shared__ float ap[256];
  const int tid = threadIdx.x;
  // avg_prob reduction: 2048 router blocks x 8 experts
  {
    const int e = tid & 7, chunk = tid >> 3;    // 32 chunks of 64 blocks
    float s = 0.f;
    #pragma unroll 8
    for (int i = 0; i < 64; ++i)
      s += avg_part[(chunk*64 + i)*E_NUM + e];
    ap[tid] = s;
  }
  // counts reduction: 32 hist blocks x 8 experts
  if (tid < E_NUM){
    int c = 0;
    #pragma unroll
    for (int b = 0; b < HB; ++b) c += block_hist[b*E_NUM + tid];
    counts[tid] = c;
  }
  __syncthreads();
  if (tid < E_NUM){
    float tot = 0.f;
    #pragma unroll
    for (int c = 0; c < 32; ++c) tot += ap[c*8 + tid];
    out[OUT_AVG  + tid] = tot * (1.f/8192.f);
    out[OUT_FRAC + tid] = (float)counts[tid] * (1.f/16384.f);
  }
  if (tid == 0){
    int base = 0, tt = 0;
    for (int e=0;e<E_NUM;e++){
      int run = base;
      for (int b=0;b<HB;b++){
        block_base[b*E_NUM + e] = run;
        run += block_hist[b*E_NUM + e];
      }
      int nt = (counts[e] + BM - 1) / BM;
      for (int i=0;i<nt;i++){ tile_e[tt] = e; tile_r[tt] = base + i*BM; tt++; }
      base += nt * BM;
    }
    hdr[0] = tt; hdr[1] = base;
  }
  for (int i = tid; i < PADMAX; i += blockDim.x){
    s_tok[i] = 0; s_wt[i] = 0.f;
  }
}

// ---------------- scatter: local rank via LDS atomics + precomputed block base ----------------
__global__ __launch_bounds__(256) void scatter_kernel(const int* __restrict__ pe,
    const float* __restrict__ pw, const int* __restrict__ block_base,
    int* __restrict__ s_tok, float* __restrict__ s_wt, int* __restrict__ slot_idx){
  __shared__ int h[E_NUM];
  if (threadIdx.x < E_NUM) h[threadIdx.x] = 0;
  __syncthreads();
  const int base = blockIdx.x * PAIRS_PER_HB;
  for (int i = threadIdx.x; i < PAIRS_PER_HB; i += 256){
    const int pi = base + i;
    const int e = pe[pi];
    const int r = atomicAdd(&h[e], 1);
    const int idx = block_base[blockIdx.x*E_NUM + e] + r;
    s_tok[idx] = pi >> 1;
    s_wt[idx]  = pw[pi];
    slot_idx[pi] = idx;
  }
}

// ---------------- gate+up GEMM: 128x128 tile, 256 thr (4 waves), 3-buf, 2 blocks/CU ----------------
__global__ __launch_bounds__(256, 2) void gateup_kernel(
    const ushort* __restrict__ xb, const ushort* __restrict__ gwb,
    const ushort* __restrict__ uwb, const int* __restrict__ s_tok,
    const int* __restrict__ tile_e, const int* __restrict__ tile_r,
    const int* __restrict__ hdr, ushort* __restrict__ h1)
{
  const int tile = blockIdx.y;
  if (tile >= hdr[0]) return;
  __shared__ short sA[3][BM*BK2];
  __shared__ short sG[3][BM*BK2];
  __shared__ short sU[3][BM*BK2];     // 72 KB -> 2 blocks/CU
  const int e = tile_e[tile];
  const int row0 = tile_r[tile];
  const int n0 = blockIdx.x * 128;
  const int tid = threadIdx.x, lane = tid & 63, wid = tid >> 6;

  const int srow = tid >> 2;
  const int scg  = ((tid & 3) ^ ((tid >> 3) & 3)) * 8;
  const int d0 = tid * 8, d1 = tid * 8 + 2048;
  const ushort* gA0 = xb  + (size_t)s_tok[row0 + srow]      * H_DIM + scg;
  const ushort* gA1 = xb  + (size_t)s_tok[row0 + srow + 64] * H_DIM + scg;
  const ushort* gG0 = gwb + ((size_t)e*I_DIM + n0 + srow)      * H_DIM + scg;
  const ushort* gG1 = gwb + ((size_t)e*I_DIM + n0 + srow + 64) * H_DIM + scg;
  const ushort* gU0 = uwb + ((size_t)e*I_DIM + n0 + srow)      * H_DIM + scg;
  const ushort* gU1 = uwb + ((size_t)e*I_DIM + n0 + srow + 64) * H_DIM + scg;

  const int wm = (wid >> 1) * 64, wn = (wid & 1) * 64;
  const int lr = lane & 15, q = lane >> 4;
  const int swc = (q ^ ((lr >> 1) & 3)) * 8;

  f32x4 accG[4][4] = {};
  f32x4 accU[4][4] = {};

  gload16(gA0,       &sA[0][d0]); gload16(gA1,       &sA[0][d1]);
  gload16(gG0,       &sG[0][d0]); gload16(gG1,       &sG[0][d1]);
  gload16(gU0,       &sU[0][d0]); gload16(gU1,       &sU[0][d1]);
  gload16(gA0 + BK2, &sA[1][d0]); gload16(gA1 + BK2, &sA[1][d1]);
  gload16(gG0 + BK2, &sG[1][d0]); gload16(gG1 + BK2, &sG[1][d1]);
  gload16(gU0 + BK2, &sU[1][d0]); gload16(gU1 + BK2, &sU[1][d1]);
  WAITV6_BAR;

  const int NK = H_DIM / BK2;   // 32
  int b0 = 0, b1 = 1, b2 = 2;
  for (int kt = 0; kt < NK; ++kt){
    short8v a_[4], bg_[4], bu_[4];
    #pragma unroll
    for (int mi=0;mi<4;mi++)
      a_[mi] = *(const short8v*)&sA[b0][(wm + mi*16 + lr)*BK2 + swc];
    #pragma unroll
    for (int ni=0;ni<4;ni++)
      bg_[ni] = *(const short8v*)&sG[b0][(wn + ni*16 + lr)*BK2 + swc];
    if (kt + 2 < NK){
      const int kof = (kt+2)*BK2;
      gload16(gA0 + kof, &sA[b2][d0]); gload16(gA1 + kof, &sA[b2][d1]);
      gload16(gG0 + kof, &sG[b2][d0]); gload16(gG1 + kof, &sG[b2][d1]);
    }
    SCHED0; SBAR; SCHED0;
    __builtin_amdgcn_s_setprio(1);
    #pragma unroll
    for (int ni=0;ni<4;ni++)
      #pragma unroll
      for (int mi=0;mi<4;mi++)
        accG[mi][ni] = __builtin_amdgcn_mfma_f32_16x16x32_bf16(a_[mi], bg_[ni], accG[mi][ni], 0,0,0);
    __builtin_amdgcn_s_setprio(0);
    SCHED0; SBAR;
    #pragma unroll
    for (int ni=0;ni<4;ni++)
      bu_[ni] = *(const short8v*)&sU[b0][(wn + ni*16 + lr)*BK2 + swc];
    if (kt + 2 < NK){
      const int kof = (kt+2)*BK2;
      gload16(gU0 + kof, &sU[b2][d0]); gload16(gU1 + kof, &sU[b2][d1]);
    }
    SCHED0; SBAR; SCHED0;
    __builtin_amdgcn_s_setprio(1);
    #pragma unroll
    for (int ni=0;ni<4;ni++)
      #pragma unroll
      for (int mi=0;mi<4;mi++)
        accU[mi][ni] = __builtin_amdgcn_mfma_f32_16x16x32_bf16(a_[mi], bu_[ni], accU[mi][ni], 0,0,0);
    __builtin_amdgcn_s_setprio(0);
    SCHED0;
    if (kt + 2 < NK)      WAITV6_BAR;
    else if (kt + 1 < NK) WAITV0_BAR;
    int tb = b0; b0 = b1; b1 = b2; b2 = tb;
  }

  #pragma unroll
  for (int mi=0;mi<4;mi++){
    #pragma unroll
    for (int r=0;r<4;r++){
      const int row = row0 + wm + mi*16 + q*4 + r;
      ushort* hp = h1 + (size_t)row * I_DIM + n0 + wn + lr;
      #pragma unroll
      for (int ni=0;ni<4;ni++){
        float g = accG[mi][ni][r], u = accU[mi][ni][r];
        float sv = g / (1.f + __expf(-g));
        hp[ni*16] = (ushort)f2bf(sv * u);
      }
    }
  }
}

// ---------------- down GEMM: 128x128 tile, 256 thr, 3-buf, 3 blocks/CU ----------------
__global__ __launch_bounds__(256, 3) void down_kernel(
    const ushort* __restrict__ h1, const ushort* __restrict__ dwb,
    const int* __restrict__ tile_e, const int* __restrict__ tile_r,
    const int* __restrict__ hdr, ushort* __restrict__ ds_out)
{
  const int tile = blockIdx.y;
  if (tile >= hdr[0]) return;
  __shared__ short sA[3][BM*BK2];
  __shared__ short sB[3][BM*BK2];     // 48 KB -> 3 blocks/CU
  const int e = tile_e[tile];
  const int row0 = tile_r[tile];
  const int n0 = blockIdx.x * 128;
  const int tid = threadIdx.x, lane = tid & 63, wid = tid >> 6;

  const int srow = tid >> 2;
  const int scg  = ((tid & 3) ^ ((tid >> 3) & 3)) * 8;
  const int d0 = tid * 8, d1 = tid * 8 + 2048;
  const ushort* gA0 = h1  + (size_t)(row0 + srow)      * I_DIM + scg;
  const ushort* gA1 = h1  + (size_t)(row0 + srow + 64) * I_DIM + scg;
  const ushort* gB0 = dwb + ((size_t)e*H_DIM + n0 + srow)      * I_DIM + scg;
  const ushort* gB1 = dwb + ((size_t)e*H_DIM + n0 + srow + 64) * I_DIM + scg;

  const int wm = (wid >> 1) * 64, wn = (wid & 1) * 64;
  const int lr = lane & 15, q = lane >> 4;
  const int swc = (q ^ ((lr >> 1) & 3)) * 8;

  f32x4 acc[4][4] = {};

  gload16(gA0,       &sA[0][d0]); gload16(gA1,       &sA[0][d1]);
  gload16(gB0,       &sB[0][d0]); gload16(gB1,       &sB[0][d1]);
  gload16(gA0 + BK2, &sA[1][d0]); gload16(gA1 + BK2, &sA[1][d1]);
  gload16(gB0 + BK2, &sB[1][d0]); gload16(gB1 + BK2, &sB[1][d1]);
  WAITV4_BAR;

  const int NK = I_DIM / BK2;   // 64
  int b0 = 0, b1 = 1, b2 = 2;
  for (int kt = 0; kt < NK; ++kt){
    short8v a_[4], b_[4];
    #pragma unroll
    for (int mi=0;mi<4;mi++)
      a_[mi] = *(const short8v*)&sA[b0][(wm + mi*16 + lr)*BK2 + swc];
    #pragma unroll
    for (int ni=0;ni<2;ni++)
      b_[ni] = *(const short8v*)&sB[b0][(wn + ni*16 + lr)*BK2 + swc];
    if (kt + 2 < NK){
      const int kof = (kt+2)*BK2;
      gload16(gA0 + kof, &sA[b2][d0]); gload16(gA1 + kof, &sA[b2][d1]);
    }
    SCHED0; SBAR; SCHED0;
    __builtin_amdgcn_s_setprio(1);
    #pragma unroll
    for (int ni=0;ni<2;ni++)
      #pragma unroll
      for (int mi=0;mi<4;mi++)
        acc[mi][ni] = __builtin_amdgcn_mfma_f32_16x16x32_bf16(a_[mi], b_[ni], acc[mi][ni], 0,0,0);
    __builtin_amdgcn_s_setprio(0);
    SCHED0; SBAR;
    #pragma unroll
    for (int ni=2;ni<4;ni++)
      b_[ni] = *(const short8v*)&sB[b0][(wn + ni*16 + lr)*BK2 + swc];
    if (kt + 2 < NK){
      const int kof = (kt+2)*BK2;
      gload16(gB0 + kof, &sB[b2][d0]); gload16(gB1 + kof, &sB[b2][d1]);
    }
    SCHED0; SBAR; SCHED0;
    __builtin_amdgcn_s_setprio(1);
    #pragma unroll
    for (int ni=2;ni<4;ni++)
      #pragma unroll
      for (int mi=0;mi<4;mi++)
        acc[mi][ni] = __builtin_amdgcn_mfma_f32_16x16x32_bf16(a_[mi], b_[ni], acc[mi][ni], 0,0,0);
    __builtin_amdgcn_s_setprio(0);
    SCHED0;
    if (kt + 2 < NK)      WAITV4_BAR;
    else if (kt + 1 < NK) WAITV0_BAR;
    int tb = b0; b0 = b1; b1 = b2; b2 = tb;
  }

  #pragma unroll
  for (int mi=0;mi<4;mi++){
    #pragma unroll
    for (int r=0;r<4;r++){
      const int prow = row0 + wm + mi*16 + q*4 + r;
      ushort* op = ds_out + (size_t)prow * H_DIM + n0 + wn + lr;
      #pragma unroll
      for (int ni=0;ni<4;ni++)
        op[ni*16] = (ushort)f2bf(acc[mi][ni][r]);
    }
  }
}

// ---------------- combine: out[t] = w1*ds[s1] + w2*ds[s2] ----------------
__global__ __launch_bounds__(256) void combine_kernel(const ushort* __restrict__ ds_out,
    const int* __restrict__ slot_idx, const float* __restrict__ s_wt,
    float* __restrict__ out){
  const int t   = blockIdx.x * 2 + (threadIdx.x >> 7);
  const int col = (threadIdx.x & 127) * 8;
  const int s1 = slot_idx[2*t], s2 = slot_idx[2*t+1];
  const float w1 = s_wt[s1], w2 = s_wt[s2];
  const u32x4 a = *(const u32x4*)(ds_out + (size_t)s1 * H_DIM + col);
  const u32x4 b = *(const u32x4*)(ds_out + (size_t)s2 * H_DIM + col);
  float* op = out + (size_t)t * H_DIM + col;
  f32x4 o0, o1;
  o0.x = w1*bflo(a.x) + w2*bflo(b.x);
  o0.y = w1*bfhi(a.x) + w2*bfhi(b.x);
  o0.z = w1*bflo(a.y) + w2*bflo(b.y);
  o0.w = w1*bfhi(a.y) + w2*bfhi(b.y);
  o1.x = w1*bflo(a.z) + w2*bflo(b.z);
  o1.y = w1*bfhi(a.z) + w2*bfhi(b.z);
  o1.z = w1*bflo(a.w) + w2*bflo(b.w);
  o1.w = w1*bfhi(a.w) + w2*bfhi(b.w);
  *(f32x4*)op       = o0;
  *(f32x4*)(op + 4) = o1;
}

extern "C" void kernel_launch(void* const* d_in, const int* in_sizes, int n_in,
                              void* d_out, int out_size, void* d_ws, size_t ws_size,
                              hipStream_t stream){
  const float* x   = (const float*)d_in[0];
  const float* rw  = (const float*)d_in[1];
  const float* gw  = (const float*)d_in[2];
  const float* uw  = (const float*)d_in[3];
  const float* dwn = (const float*)d_in[4];
  float* out = (float*)d_out;

  char* w = (char*)d_ws;
  int*   hdr        = (int*)(w + 0);
  int*   tile_e     = (int*)(w + 256);
  int*   tile_r     = (int*)(w + 1280);
  int*   block_hist = (int*)(w + 2304);                   // 32*8 ints
  int*   block_base = (int*)(w + 3328);                   // 32*8 ints
  int*   s_tok      = (int*)(w + 8192);                   // PADMAX*4
  float* s_wt       = (float*)(w + 8192 + PADMAX*4);
  int*   pe         = (int*)(w + 8192 + PADMAX*8);
  float* pw         = (float*)(w + 8192 + PADMAX*8 + T_TOK*2*4);
  int*   slot_idx   = (int*)(w + 8192 + PADMAX*8 + T_TOK*2*8);
  float* avg_part   = (float*)(w + 8192 + PADMAX*8 + T_TOK*2*12);   // 2048*8 f32
  ushort* xb        = (ushort*)(w + 409600);
  ushort* h1        = (ushort*)(w + 409600 + (size_t)T_TOK*H_DIM*2);
  ushort* gwb       = (ushort*)(w + 409600 + (size_t)T_TOK*H_DIM*2 + (size_t)PADMAX*I_DIM*2);
  ushort* uwb       = gwb + (size_t)E_NUM*I_DIM*H_DIM;
  ushort* dwb       = uwb + (size_t)E_NUM*I_DIM*H_DIM;
  ushort* ds_out    = gwb;   // overlay: gwb/uwb dead after gateup

  size_t need = 409600 + (size_t)T_TOK*H_DIM*2 + (size_t)PADMAX*I_DIM*2
              + 3ull * E_NUM*I_DIM*H_DIM * 2;
  if (ws_size < need){
    fprintf(stderr, "kernel_launch: ws too small (%zu < %zu)\n", ws_size, need);
    return;
  }

  convert4_kernel<<<NXB + 3*NWB, 256, 0, stream>>>(x, gw, uw, dwn, xb, gwb, uwb, dwb);
  router_kernel<<<T_TOK/4, 256, 0, stream>>>(x, rw, out, pe, pw, avg_part);
  hist_kernel<<<HB, 256, 0, stream>>>(pe, block_hist);
  offsets_kernel<<<1, 256, 0, stream>>>(block_hist, avg_part, block_base,
                                        tile_e, tile_r, hdr, s_tok, s_wt, out);
  scatter_kernel<<<HB, 256, 0, stream>>>(pe, pw, block_base, s_tok, s_wt, slot_idx);
  gateup_kernel<<<dim3(I_DIM/128, MAX_TILES), 256, 0, stream>>>(xb, gwb, uwb, s_tok, tile_e, tile_r, hdr, h1);
  down_kernel<<<dim3(H_DIM/128, MAX_TILES), 256, 0, stream>>>(h1, dwb, tile_e, tile_r, hdr, ds_out);
  combine_kernel<<<T_TOK/2, 256, 0, stream>>>(ds_out, slot_idx, s_wt, out);
}